// Round 11
// baseline (4450.176 us; speedup 1.0000x reference)
//
#include <hip/hip_runtime.h>

#define HD 64
#define BT 16          // batch tile per block
#define L2E 1.4426950408889634f

typedef _Float16 v8h __attribute__((ext_vector_type(8)));
typedef _Float16 v2h __attribute__((ext_vector_type(2)));
typedef float    v4f __attribute__((ext_vector_type(4)));

__device__ __forceinline__ float fexp2(float x) { return __builtin_amdgcn_exp2f(x); }
__device__ __forceinline__ float frcp(float x)  { return __builtin_amdgcn_rcpf(x); }
__device__ __forceinline__ float fsig(float x)  { return frcp(fexp2(-L2E * x) + 1.f); }
__device__ __forceinline__ float ftanh_fast(float x) {
    return 1.f - 2.f * frcp(fexp2(2.f * L2E * x) + 1.f);
}

#define MFMA16(A, Bf, C) __builtin_amdgcn_mfma_f32_16x16x32_f16((A), (Bf), (C), 0, 0, 0)

__device__ __forceinline__ v2h pk2h(float a, float b) {
    return __builtin_bit_cast(v2h, __builtin_amdgcn_cvt_pkrtz(a, b));
}

__device__ __forceinline__ v8h cvt8(const float* p) {
    float4 a = ((const float4*)p)[0];
    float4 b = ((const float4*)p)[1];
    v8h r;
    r[0]=(_Float16)a.x; r[1]=(_Float16)a.y; r[2]=(_Float16)a.z; r[3]=(_Float16)a.w;
    r[4]=(_Float16)b.x; r[5]=(_Float16)b.y; r[6]=(_Float16)b.z; r[7]=(_Float16)b.w;
    return r;
}

// R10's validated MFMA dataflow, restructured for latency hiding:
// 1024 threads = 16 waves, grid = B/16. Wave roles (m = wave&7, tiles 2m,2m+1):
//   Waves 0-7  (L0): layer-0 gates (Whh0 A-frags) + c0/h0 update, t = i.
//   Waves 8-15 (L1): xproj (Wih1, t=i-1) with xp kept IN REGISTERS (same wave
//                    owns the matching gates1 tiles) + layer-1 gates (Whh1,
//                    t=i-2) + c1/h1 update. Wave 8: output head (t=i-3) from
//                    its already-loaded h1 B-frags — no extra LDS reads.
// Same lag pipeline / parity double-buffering / edge guards as R10 (validated
// absmax 2.44e-4). 4 waves/SIMD; per-wave serial chain ~half of R10's.
__launch_bounds__(1024, 1)
__global__ void lstm2_kernel(const float* __restrict__ x,     // [B,T]
                             const float* __restrict__ h0in,  // [2,B,HD]
                             const float* __restrict__ c0in,  // [2,B,HD]
                             const float* __restrict__ Wih0,  // [4H,1]
                             const float* __restrict__ Whh0,  // [4H,HD]
                             const float* __restrict__ bih0,
                             const float* __restrict__ bhh0,
                             const float* __restrict__ Wih1,  // [4H,HD]
                             const float* __restrict__ Whh1,  // [4H,HD]
                             const float* __restrict__ bih1,
                             const float* __restrict__ bhh1,
                             const float* __restrict__ Wlin,  // [1,HD]
                             const float* __restrict__ blin,  // [1]
                             float* __restrict__ out,         // [B,T]
                             int B, int T)
{
    const int bb   = blockIdx.x * BT;
    const int tid  = threadIdx.x;
    const int wave = tid >> 6;
    const int lane = tid & 63;
    const int m    = wave & 7;             // tile-group (units 8m..8m+7)
    const int q    = lane >> 4;
    const int n    = lane & 15;
    const int ulA  = (lane & 15) >> 2;
    const int gA   = (lane & 15) & 3;
    const bool isL0 = (wave < 8);

    __shared__ __align__(16) _Float16 h0l[2][BT][72];  // [par][n][unit]
    __shared__ __align__(16) _Float16 h1l[2][BT][72];
    __shared__ float xl[2][BT][65];

    // ---- zero-init all LDS (launch-history independence) ----
    { _Float16* p0 = &h0l[0][0][0]; _Float16* p1 = &h1l[0][0][0];
      for (int idx = tid; idx < 2 * BT * 72; idx += 1024) { p0[idx] = (_Float16)0.f; p1[idx] = (_Float16)0.f; }
      float* px = &xl[0][0][0];
      for (int idx = tid; idx < 2 * BT * 65; idx += 1024) px[idx] = 0.f; }
    __syncthreads();

    // ---- per-role A-fragments: rows r = gA*64 + (8m + 2*ulA + tile) ----
    v8h wA[2][2], wB[2][2], wC[2][2];
    #pragma unroll
    for (int t = 0; t < 2; ++t) {
        const int r = gA * HD + (8 * m + 2 * ulA + t);
        #pragma unroll
        for (int c = 0; c < 2; ++c) {
            const int k0 = 32 * c + 8 * q;
            if (isL0) {
                wA[t][c] = cvt8(Whh0 + r * HD + k0);
            } else {
                wB[t][c] = cvt8(Wih1 + r * HD + k0);
                wC[t][c] = cvt8(Whh1 + r * HD + k0);
            }
        }
    }

    // ---- consumer-side constants: unit u = 8m + 2q + t ----
    v4f b0v[2], wx0v[2], b1v[2];
    float c0s[2] = {0.f, 0.f}, c1s[2] = {0.f, 0.f};
    #pragma unroll
    for (int t = 0; t < 2; ++t) {
        const int u = 8 * m + 2 * q + t;
        #pragma unroll
        for (int g = 0; g < 4; ++g) {
            const int r = g * HD + u;
            if (isL0) {
                b0v[t][g]  = bih0[r] + bhh0[r];
                wx0v[t][g] = Wih0[r];
            } else {
                b1v[t][g]  = bih1[r] + bhh1[r];
            }
        }
        if (isL0) c0s[t] = c0in[(bb + n) * HD + u];
        else      c1s[t] = c0in[(size_t)B * HD + (bb + n) * HD + u];
    }
    {   // h state init into parity 1
        const int u0 = 8 * m + 2 * q;
        if (isL0)
            *(v2h*)&h0l[1][n][u0] = pk2h(
                h0in[(bb + n) * HD + u0], h0in[(bb + n) * HD + u0 + 1]);
        else
            *(v2h*)&h1l[1][n][u0] = pk2h(
                h0in[(size_t)B * HD + (bb + n) * HD + u0],
                h0in[(size_t)B * HD + (bb + n) * HD + u0 + 1]);
    }

    // head weights (wave 8): pairs matching this lane's h1 B-frag units:
    //   s=0..3 -> units 8q+2s, 8q+2s+1 ; s=4..7 -> units 32+8q+2(s-4), +1
    v2h wlp[8];
    if (wave == 8) {
        #pragma unroll
        for (int s = 0; s < 4; ++s) {
            wlp[s]     = v2h{(_Float16)Wlin[8 * q + 2 * s],
                             (_Float16)Wlin[8 * q + 2 * s + 1]};
            wlp[s + 4] = v2h{(_Float16)Wlin[32 + 8 * q + 2 * s],
                             (_Float16)Wlin[32 + 8 * q + 2 * s + 1]};
        }
    }
    const float blin0 = blin[0];

    // preload x chunk 0 (1024 threads -> exactly one element each)
    for (int idx = tid; idx < BT * 64; idx += 1024) {
        const int nn = idx >> 6, tt = idx & 63;
        xl[0][nn][tt] = x[(bb + nn) * T + tt];
    }

    v4f xp[2][2];
    #pragma unroll
    for (int t = 0; t < 2; ++t) { xp[0][t] = v4f{0.f,0.f,0.f,0.f}; xp[1][t] = xp[0][t]; }

    for (int i = 0; i <= T + 2; ++i) {
        __syncthreads();

        // stage next x chunk (visible after next barrier)
        if (((i + 1) & 63) == 0 && (i + 1) < T) {
            const int ib = i + 1, buf = (ib >> 6) & 1;
            for (int idx = tid; idx < BT * 64; idx += 1024) {
                const int nn = idx >> 6, tt = idx & 63;
                xl[buf][nn][tt] = x[(bb + nn) * T + ib + tt];
            }
        }

        const int pr = (i + 1) & 1;       // read parity
        const int pw = i & 1;             // write parity

        if (isL0) {
            if (i < T) {                  // gates0(t=i) + layer-0 update
                const v8h f0c0 = *(const v8h*)&h0l[pr][n][8 * q];
                const v8h f0c1 = *(const v8h*)&h0l[pr][n][32 + 8 * q];
                const float xv = xl[(i >> 6) & 1][n][i & 63];
                float hn[2];
                #pragma unroll
                for (int t = 0; t < 2; ++t) {
                    v4f ci;
                    #pragma unroll
                    for (int g = 0; g < 4; ++g) ci[g] = fmaf(wx0v[t][g], xv, b0v[t][g]);
                    v4f d = MFMA16(wA[t][0], f0c0, ci);
                    d = MFMA16(wA[t][1], f0c1, d);
                    const float si = fsig(d[0]), sf = fsig(d[1]);
                    const float tg = ftanh_fast(d[2]), so = fsig(d[3]);
                    c0s[t] = fmaf(sf, c0s[t], si * tg);
                    hn[t]  = so * ftanh_fast(c0s[t]);
                }
                *(v2h*)&h0l[pw][n][8 * m + 2 * q] = pk2h(hn[0], hn[1]);
            }
        } else {
            if (i >= 1 && i <= T) {       // xproj(t=i-1), xp stays in registers
                const v8h f0c0 = *(const v8h*)&h0l[pr][n][8 * q];
                const v8h f0c1 = *(const v8h*)&h0l[pr][n][32 + 8 * q];
                #pragma unroll
                for (int t = 0; t < 2; ++t) {
                    v4f d = MFMA16(wB[t][0], f0c0, b1v[t]);
                    xp[pr][t] = MFMA16(wB[t][1], f0c1, d);
                }
            }
            if (i >= 2) {                 // h1(i-3) B-frags (also feed the head)
                const v8h f1c0 = *(const v8h*)&h1l[pr][n][8 * q];
                const v8h f1c1 = *(const v8h*)&h1l[pr][n][32 + 8 * q];
                if (i <= T + 1) {         // gates1(t=i-2): C = xp(t=i-2)
                    float hn[2];
                    #pragma unroll
                    for (int t = 0; t < 2; ++t) {
                        v4f d = MFMA16(wC[t][0], f1c0, xp[pw][t]);
                        d = MFMA16(wC[t][1], f1c1, d);
                        const float si = fsig(d[0]), sf = fsig(d[1]);
                        const float tg = ftanh_fast(d[2]), so = fsig(d[3]);
                        c1s[t] = fmaf(sf, c1s[t], si * tg);
                        hn[t]  = so * ftanh_fast(c1s[t]);
                    }
                    *(v2h*)&h1l[pw][n][8 * m + 2 * q] = pk2h(hn[0], hn[1]);
                }
                if (wave == 8 && i >= 3) {  // head(t=i-3) from B-frag registers
                    const v2h* pc0 = (const v2h*)&f1c0;
                    const v2h* pc1 = (const v2h*)&f1c1;
                    float p = 0.f;
                    #pragma unroll
                    for (int s = 0; s < 4; ++s) {
                        p = __builtin_amdgcn_fdot2(wlp[s],     pc0[s], p, false);
                        p = __builtin_amdgcn_fdot2(wlp[s + 4], pc1[s], p, false);
                    }
                    p += __shfl_xor(p, 16, 64);
                    p += __shfl_xor(p, 32, 64);
                    if (lane < 16) out[(bb + n) * T + (i - 3)] = p + blin0;
                }
            }
        }
    }
}

extern "C" void kernel_launch(void* const* d_in, const int* in_sizes, int n_in,
                              void* d_out, int out_size, void* d_ws, size_t ws_size,
                              hipStream_t stream)
{
    const float* x    = (const float*)d_in[0];
    const float* h0   = (const float*)d_in[1];
    const float* c0   = (const float*)d_in[2];
    const float* Wih0 = (const float*)d_in[3];
    const float* Whh0 = (const float*)d_in[4];
    const float* bih0 = (const float*)d_in[5];
    const float* bhh0 = (const float*)d_in[6];
    const float* Wih1 = (const float*)d_in[7];
    const float* Whh1 = (const float*)d_in[8];
    const float* bih1 = (const float*)d_in[9];
    const float* bhh1 = (const float*)d_in[10];
    const float* Wlin = (const float*)d_in[11];
    const float* blin = (const float*)d_in[12];
    float* out = (float*)d_out;

    const int B = in_sizes[1] / (2 * HD);   // h0 is [2,B,HD]
    const int T = in_sizes[0] / B;          // input is [B,T]

    lstm2_kernel<<<dim3(B / BT), dim3(1024), 0, stream>>>(
        x, h0, c0, Wih0, Whh0, bih0, bhh0,
        Wih1, Whh1, bih1, bhh1, Wlin, blin, out, B, T);
}

// Round 12
// 1766.208 us; speedup vs baseline: 2.5196x; 2.5196x over previous
//
#include <hip/hip_runtime.h>

#define HD 64
#define TMAX 2048
#define L2E 1.4426950408889634f

typedef _Float16 v8h __attribute__((ext_vector_type(8)));
typedef _Float16 v2h __attribute__((ext_vector_type(2)));
typedef float    v4f __attribute__((ext_vector_type(4)));

__device__ __forceinline__ float fexp2(float x) { return __builtin_amdgcn_exp2f(x); }
__device__ __forceinline__ float frcp(float x)  { return __builtin_amdgcn_rcpf(x); }
__device__ __forceinline__ float fsig(float x)  { return frcp(fexp2(-L2E * x) + 1.f); }
__device__ __forceinline__ float ftanh_fast(float x) {
    return 1.f - 2.f * frcp(fexp2(2.f * L2E * x) + 1.f);
}

#define MFMA16(A, Bf, C) __builtin_amdgcn_mfma_f32_16x16x32_f16((A), (Bf), (C), 0, 0, 0)

__device__ __forceinline__ v8h cvt8(const float* p) {
    float4 a = ((const float4*)p)[0];
    float4 b = ((const float4*)p)[1];
    v8h r;
    r[0]=(_Float16)a.x; r[1]=(_Float16)a.y; r[2]=(_Float16)a.z; r[3]=(_Float16)a.w;
    r[4]=(_Float16)b.x; r[5]=(_Float16)b.y; r[6]=(_Float16)b.z; r[7]=(_Float16)b.w;
    return r;
}

// BT=1, grid=B (every CU), 256 threads = 4 FREE-RUNNING waves, NO barrier in
// the time loop. Sync = LDS spin-flags (monotonic step counters), 4-slot rings.
//   W0: layer-0. 16 M-tiles of Whh0 in regs (R10-validated A layout). MFMA
//       columns are replicated (B bcast) -> each lane activates ONLY tile n
//       (cndmask select, 10 trans/lane). 64 lanes -> 64 h units -> ds_write_b16
//       -> in-wave-ordered readback as next B-frag. Recurrence never syncs.
//   W1: xproj (Wih1): reads h0 ring, publishes its tile-n C (v4f) to xpr ring.
//   W2: layer-1 recurrence (Whh1): MFMA C-init = xpr (1 b128), h1 self-fed
//       like W0.  W3: head: Wlin dot h1 ring + reduce + store.
// Unit mapping: tile t covers units u(t,q)= t<8 ? 8q+t : 32+8q+(t-8); lane
// (q,n) owns unit u(n,q); its B-frag chunk k=8q+j is exactly units 8q+j. Flags:
// f0/fxp/f1 = producer step done; c1/c2/c3 = consumer step done (backpressure,
// ring depth 4). Single-producer single-reader monotonic ints; producer fences
// (threadfence_block) before flag write; DS in-wave ordering covers self-reads.
__launch_bounds__(256, 1)
__global__ void lstm2_kernel(const float* __restrict__ x,     // [B,T]
                             const float* __restrict__ h0in,  // [2,B,HD]
                             const float* __restrict__ c0in,  // [2,B,HD]
                             const float* __restrict__ Wih0,  // [4H,1]
                             const float* __restrict__ Whh0,  // [4H,HD]
                             const float* __restrict__ bih0,
                             const float* __restrict__ bhh0,
                             const float* __restrict__ Wih1,  // [4H,HD]
                             const float* __restrict__ Whh1,  // [4H,HD]
                             const float* __restrict__ bih1,
                             const float* __restrict__ bhh1,
                             const float* __restrict__ Wlin,  // [1,HD]
                             const float* __restrict__ blin,  // [1]
                             float* __restrict__ out,         // [B,T]
                             int B, int T)
{
    const int b    = blockIdx.x;
    const int tid  = threadIdx.x;
    const int wave = tid >> 6;
    const int lane = tid & 63;
    const int q    = lane >> 4;            // B k-group / C quad
    const int n    = lane & 15;            // column = this lane's owned tile
    const int u    = (n < 8) ? (8*q + n) : (32 + 8*q + (n - 8)); // owned unit

    __shared__ float xs[TMAX];
    __shared__ _Float16 h0r[4][HD];        // h0 ring (f16), slot = t&3
    __shared__ _Float16 h1r[4][HD];
    __shared__ __align__(16) float xpr[4][4][16][4]; // [slot][q][tile][gate]
    __shared__ int flg[8];                 // 0:f0 1:fxp 2:f1 3:c1 4:c2 5:c3
    volatile int* vf = (volatile int*)flg;

    for (int i = tid; i < T; i += 256) xs[i] = x[b * T + i];
    if (tid < 8) flg[tid] = -1;
    __syncthreads();                       // the ONLY barrier

    // A-frag addressing (R10-validated): lane m=lane&15 -> gate gm=m&3,
    // unit-quad qm=m>>2; k = 32*chunk + 8*(lane>>4) + j
    const int ml = lane & 15, gm = ml & 3, qm = ml >> 2, kq = lane >> 4;

    if (wave == 0) {                       // ---------------- layer 0
        v8h wA[16][2];
        #pragma unroll
        for (int t = 0; t < 16; ++t) {
            const int ut = (t < 8) ? (8*qm + t) : (32 + 8*qm + (t - 8));
            const int r  = gm * HD + ut;
            wA[t][0] = cvt8(Whh0 + r * HD + 8 * kq);
            wA[t][1] = cvt8(Whh0 + r * HD + 32 + 8 * kq);
        }
        float b0v[4], wx0v[4];
        #pragma unroll
        for (int g = 0; g < 4; ++g) {
            const int r = g * HD + u;
            b0v[g]  = bih0[r] + bhh0[r];
            wx0v[g] = Wih0[r];
        }
        float cst = c0in[b * HD + u];
        v8h hc0 = cvt8(h0in + b * HD + 8 * q);
        v8h hc1 = cvt8(h0in + b * HD + 32 + 8 * q);

        int c1c = -1;                      // cached consumer flag
        for (int t = 0; t < T; ++t) {
            if (c1c < t - 4) { do { c1c = vf[3]; if (c1c >= t - 4) break; __builtin_amdgcn_s_sleep(2); } while (1); }
            const float xv = xs[t];
            v4f ci;
            #pragma unroll
            for (int g = 0; g < 4; ++g) ci[g] = fmaf(wx0v[g], xv, b0v[g]);
            v4f sel = ci;
            #pragma unroll
            for (int tt = 0; tt < 16; ++tt) {
                v4f d = MFMA16(wA[tt][0], hc0, ci);
                d = MFMA16(wA[tt][1], hc1, d);
                sel = (tt == n) ? d : sel;
            }
            const float si = fsig(sel[0]), sf = fsig(sel[1]);
            const float tg = ftanh_fast(sel[2]), so = fsig(sel[3]);
            cst = fmaf(sf, cst, si * tg);
            const float h = so * ftanh_fast(cst);
            h0r[t & 3][u] = (_Float16)h;   // 64 lanes -> 64 units
            __threadfence_block();
            if (lane == 0) vf[0] = t;
            hc0 = *(const v8h*)&h0r[t & 3][8 * q];        // in-wave ordered
            hc1 = *(const v8h*)&h0r[t & 3][32 + 8 * q];
        }
    } else if (wave == 1) {                // ---------------- xproj
        v8h wB[16][2];
        #pragma unroll
        for (int t = 0; t < 16; ++t) {
            const int ut = (t < 8) ? (8*qm + t) : (32 + 8*qm + (t - 8));
            const int r  = gm * HD + ut;
            wB[t][0] = cvt8(Wih1 + r * HD + 8 * kq);
            wB[t][1] = cvt8(Wih1 + r * HD + 32 + 8 * kq);
        }
        float b1v[4];
        #pragma unroll
        for (int g = 0; g < 4; ++g) b1v[g] = bih1[g * HD + u] + bhh1[g * HD + u];

        int f0c = -1, c2c = -1;
        for (int t = 0; t < T; ++t) {
            if (f0c < t)     { do { f0c = vf[0]; if (f0c >= t) break; __builtin_amdgcn_s_sleep(2); } while (1); }
            if (c2c < t - 4) { do { c2c = vf[4]; if (c2c >= t - 4) break; __builtin_amdgcn_s_sleep(2); } while (1); }
            v8h hc0 = *(const v8h*)&h0r[t & 3][8 * q];
            v8h hc1 = *(const v8h*)&h0r[t & 3][32 + 8 * q];
            v4f ci;
            #pragma unroll
            for (int g = 0; g < 4; ++g) ci[g] = b1v[g];
            v4f sel = ci;
            #pragma unroll
            for (int tt = 0; tt < 16; ++tt) {
                v4f d = MFMA16(wB[tt][0], hc0, ci);
                d = MFMA16(wB[tt][1], hc1, d);
                sel = (tt == n) ? d : sel;
            }
            *(v4f*)&xpr[t & 3][q][n][0] = sel;
            __threadfence_block();
            if (lane == 0) { vf[1] = t; vf[3] = t; }   // fxp, c1
        }
    } else if (wave == 2) {                // ---------------- layer 1
        v8h wC[16][2];
        #pragma unroll
        for (int t = 0; t < 16; ++t) {
            const int ut = (t < 8) ? (8*qm + t) : (32 + 8*qm + (t - 8));
            const int r  = gm * HD + ut;
            wC[t][0] = cvt8(Whh1 + r * HD + 8 * kq);
            wC[t][1] = cvt8(Whh1 + r * HD + 32 + 8 * kq);
        }
        float cst = c0in[(size_t)B * HD + b * HD + u];
        v8h hc0 = cvt8(h0in + (size_t)B * HD + b * HD + 8 * q);
        v8h hc1 = cvt8(h0in + (size_t)B * HD + b * HD + 32 + 8 * q);

        int fxc = -1, c3c = -1;
        for (int t = 0; t < T; ++t) {
            if (fxc < t)     { do { fxc = vf[1]; if (fxc >= t) break; __builtin_amdgcn_s_sleep(2); } while (1); }
            if (c3c < t - 4) { do { c3c = vf[5]; if (c3c >= t - 4) break; __builtin_amdgcn_s_sleep(2); } while (1); }
            v4f ci = *(const v4f*)&xpr[t & 3][q][n][0];
            v4f sel = ci;
            #pragma unroll
            for (int tt = 0; tt < 16; ++tt) {
                v4f d = MFMA16(wC[tt][0], hc0, ci);
                d = MFMA16(wC[tt][1], hc1, d);
                sel = (tt == n) ? d : sel;
            }
            const float si = fsig(sel[0]), sf = fsig(sel[1]);
            const float tg = ftanh_fast(sel[2]), so = fsig(sel[3]);
            cst = fmaf(sf, cst, si * tg);
            const float h = so * ftanh_fast(cst);
            h1r[t & 3][u] = (_Float16)h;
            __threadfence_block();
            if (lane == 0) { vf[2] = t; vf[4] = t; }   // f1, c2
            hc0 = *(const v8h*)&h1r[t & 3][8 * q];
            hc1 = *(const v8h*)&h1r[t & 3][32 + 8 * q];
        }
    } else {                               // ---------------- head
        const int li = lane & 31;
        v2h wl; wl[0] = (_Float16)Wlin[2 * li]; wl[1] = (_Float16)Wlin[2 * li + 1];
        const float bl = blin[0];
        int f1c = -1;
        for (int t = 0; t < T; ++t) {
            if (f1c < t) { do { f1c = vf[2]; if (f1c >= t) break; __builtin_amdgcn_s_sleep(2); } while (1); }
            v2h hv = *(const v2h*)&h1r[t & 3][2 * li];
            float p = __builtin_amdgcn_fdot2(wl, hv, 0.f, false);
            if (lane >= 32) p = 0.f;
            p += __shfl_xor(p, 1, 64);
            p += __shfl_xor(p, 2, 64);
            p += __shfl_xor(p, 4, 64);
            p += __shfl_xor(p, 8, 64);
            p += __shfl_xor(p, 16, 64);
            if (lane == 0) { out[b * T + t] = p + bl; vf[5] = t; }  // store + c3
        }
    }
}

extern "C" void kernel_launch(void* const* d_in, const int* in_sizes, int n_in,
                              void* d_out, int out_size, void* d_ws, size_t ws_size,
                              hipStream_t stream)
{
    const float* x    = (const float*)d_in[0];
    const float* h0   = (const float*)d_in[1];
    const float* c0   = (const float*)d_in[2];
    const float* Wih0 = (const float*)d_in[3];
    const float* Whh0 = (const float*)d_in[4];
    const float* bih0 = (const float*)d_in[5];
    const float* bhh0 = (const float*)d_in[6];
    const float* Wih1 = (const float*)d_in[7];
    const float* Whh1 = (const float*)d_in[8];
    const float* bih1 = (const float*)d_in[9];
    const float* bhh1 = (const float*)d_in[10];
    const float* Wlin = (const float*)d_in[11];
    const float* blin = (const float*)d_in[12];
    float* out = (float*)d_out;

    const int B = in_sizes[1] / (2 * HD);   // h0 is [2,B,HD]
    const int T = in_sizes[0] / B;          // input is [B,T]  (T <= TMAX)

    lstm2_kernel<<<dim3(B), dim3(256), 0, stream>>>(
        x, h0, c0, Wih0, Whh0, bih0, bhh0,
        Wih1, Whh1, bih1, bhh1, Wlin, blin, out, B, T);
}